// Round 11
// baseline (365.645 us; speedup 1.0000x reference)
//
#include <hip/hip_runtime.h>
#include <stdint.h>

// CausalMultiHeadAttention — round 9 (second resubmit; prior two benches were
// infra GPUAcquisitionTimeouts, no counters produced).
// r8 results: attn fixed (201->118 us; pairing + bh-colocation CONFIRMED).
// GEMMs unchanged at ~62 us each (grid transpose = no effect) — latency-bound
// at 2 blocks/CU with pk8 VALU staging (m90-structure ceiling ~280 TF).
// This round (GEMM only, attn byte-identical):
//  - x pre-converted fp32->bf16 once into the O slot (r6-proven placement:
//    xb dead before attn writes O).
//  - All 4 GEMMs stage A via global_load_lds width=16 (async direct-to-LDS,
//    no VGPR round-trip, no per-tile reconvert) — the m97 lever, now tested
//    WITHOUT the r6 merged-grid confounder. W stays pk8 (no ws room).
// ws: Q | K | Vt (fp16) | {xb then O} (bf16) = 67.1 MB (proven size).

#define D_MODEL 1024
#define NHEAD   16
#define DK      64
#define BATCH   4
#define SEQ     2048
#define MTOT    (BATCH*SEQ)   // 8192

typedef unsigned short u16;
typedef unsigned int   u32;
typedef __bf16    bf16x8  __attribute__((ext_vector_type(8)));
typedef float     floatx4 __attribute__((ext_vector_type(4)));
typedef __fp16    fp16x2  __attribute__((ext_vector_type(2)));
typedef _Float16  half4_t __attribute__((ext_vector_type(4)));
typedef _Float16  half8_t __attribute__((ext_vector_type(8)));

// round-to-nearest-even f32 -> bf16 (epilogue only)
__device__ __forceinline__ u16 f2bf(float f){
  union { float f; u32 u; } c; c.f = f;
  u32 x = c.u;
  x += 0x7fffu + ((x >> 16) & 1u);
  return (u16)(x >> 16);
}
// f32 pair -> packed fp16 bits (RTZ, hardware packed cvt)
__device__ __forceinline__ u32 pkh(float a, float b){
  union { fp16x2 h; u32 u; } c; c.h = __builtin_amdgcn_cvt_pkrtz(a, b); return c.u;
}
// 8 fp32 -> 8 bf16 by truncation: one v_perm per pair (staging fast path)
__device__ __forceinline__ uint4 pk8(const float* __restrict__ p){
  uint4 a = *(const uint4*)p;
  uint4 b = *(const uint4*)(p + 4);
  uint4 r;
  r.x = __builtin_amdgcn_perm(a.y, a.x, 0x07060302);
  r.y = __builtin_amdgcn_perm(a.w, a.z, 0x07060302);
  r.z = __builtin_amdgcn_perm(b.y, b.x, 0x07060302);
  r.w = __builtin_amdgcn_perm(b.w, b.z, 0x07060302);
  return r;
}
// async global->LDS, 16B per lane. LDS dest must be linear in lane order.
__device__ __forceinline__ void gload16(const void* g, void* l){
  __builtin_amdgcn_global_load_lds(
      (const __attribute__((address_space(1))) u32*)g,
      (__attribute__((address_space(3))) u32*)l, 16, 0, 0);
}

// ---------------------------------------------------------------------------
// fp32 -> bf16 trunc convert (memory-bound pre-pass for x). Exact-size grid.
// ---------------------------------------------------------------------------
__global__ __launch_bounds__(256)
void to_bf16(const float* __restrict__ s, u16* __restrict__ d)
{
  const size_t i = ((size_t)blockIdx.x * 256 + threadIdx.x) * 8;
  *(uint4*)(d + i) = pk8(s + i);
}

// ---------------------------------------------------------------------------
// GEMM: C[m,n] = (sum_k A[m,k]*W[n,k] + bias[n]) * scale.  A: MxK row-major
// bf16 (pre-converted), staged via global_load_lds.  W: NxK fp32 (nn.Linear
// weight), staged via pk8.
// 128x128 tile, BK=32, 256 thr = 4 waves in 2x2, each wave 64x64 = 4x4 MFMA.
// Grid (64 m-tiles, 8 n-tiles).
//   MODE 0 (fp32 [m][N], d_out) / MODE 1 (fp16 [bh][s][dk]): mfma(W,A) ->
//     lane=m, regs=n-consecutive -> float4 / uint2 stores.
//   MODE 2 (fp16 [bh][dk][s], V^T): mfma(A,W) -> lane=n(dd), regs=m(s)
//     -> uint2 stores contiguous in s.
// ---------------------------------------------------------------------------
template<int MODE>
__global__ __launch_bounds__(256, 2)
void gemm_bt(const u16* __restrict__ A, const float* __restrict__ W,
             const float* __restrict__ bias, void* __restrict__ outv,
             float scale)
{
  __shared__ __align__(16) u16 As[128*32];
  __shared__ __align__(16) u16 Bs[128*32];

  const int t    = threadIdx.x;
  const int m0   = blockIdx.x * 128;
  const int n0   = blockIdx.y * 128;
  const int wid  = t >> 6, lane = t & 63;
  const int wr   = wid >> 1, wc = wid & 1;
  const int quad = lane >> 4, l15 = lane & 15;

  // staging chunks: c -> row = c>>2, koff = (c&3)*8 ; LDS layout [row][32].
  // chunk c at LDS byte c*16 -> linear in lane order (gload_lds requirement).
  const int c0 = t, c1 = t + 256;
  const int r0c = c0 >> 2, k0c = (c0 & 3) * 8;
  const int r1c = c1 >> 2, k1c = (c1 & 3) * 8;

  floatx4 acc[4][4] = {};

  for (int k0 = 0; k0 < D_MODEL; k0 += 32) {
    __syncthreads();
    gload16(A + (size_t)(m0 + r0c)*D_MODEL + k0 + k0c, (char*)As + t*16);
    gload16(A + (size_t)(m0 + r1c)*D_MODEL + k0 + k1c, (char*)As + 4096 + t*16);
    *(uint4*)&Bs[c0*8] = pk8(W + (size_t)(n0 + r0c)*D_MODEL + k0 + k0c);
    *(uint4*)&Bs[c1*8] = pk8(W + (size_t)(n0 + r1c)*D_MODEL + k0 + k1c);
    __syncthreads();   // compiler emits vmcnt(0)+lgkmcnt(0) drain here

    bf16x8 af[4], bf[4];
#pragma unroll
    for (int i = 0; i < 4; ++i) {
      af[i] = *(const bf16x8*)&As[(wr*64 + i*16 + l15)*32 + quad*8];
      bf[i] = *(const bf16x8*)&Bs[(wc*64 + i*16 + l15)*32 + quad*8];
    }
#pragma unroll
    for (int mi = 0; mi < 4; ++mi)
#pragma unroll
      for (int nj = 0; nj < 4; ++nj) {
        if (MODE == 2)
          acc[mi][nj] = __builtin_amdgcn_mfma_f32_16x16x32_bf16(af[mi], bf[nj], acc[mi][nj], 0, 0, 0);
        else
          acc[mi][nj] = __builtin_amdgcn_mfma_f32_16x16x32_bf16(bf[nj], af[mi], acc[mi][nj], 0, 0, 0);
      }
  }

  if (MODE != 2) {
    // lane = m, regs = n-consecutive
#pragma unroll
    for (int nj = 0; nj < 4; ++nj) {
      const int nb = n0 + wc*64 + nj*16 + quad*4;
      const float4 b4 = *(const float4*)(bias + nb);
#pragma unroll
      for (int mi = 0; mi < 4; ++mi) {
        const int m = m0 + wr*64 + mi*16 + l15;
        floatx4 d = acc[mi][nj];
        const float v0 = (d[0]+b4.x)*scale, v1 = (d[1]+b4.y)*scale;
        const float v2 = (d[2]+b4.z)*scale, v3 = (d[3]+b4.w)*scale;
        if (MODE == 0) {
          float4 s4 = make_float4(v0, v1, v2, v3);
          *(float4*)((float*)outv + (size_t)m*D_MODEL + nb) = s4;
        } else {
          const int b = m >> 11, s = m & 2047, h = nb >> 6, dd = nb & 63;
          u16* dst = (u16*)outv + ((((size_t)b*NHEAD + h)*SEQ + s) << 6) + dd;
          *(uint2*)dst = make_uint2(pkh(v0, v1), pkh(v2, v3));
        }
      }
    }
  } else {
    // lane = n (dd), regs = m (s)-consecutive
#pragma unroll
    for (int nj = 0; nj < 4; ++nj) {
      const int n  = n0 + wc*64 + nj*16 + l15;
      const float bvv = bias[n];
      const int h = n >> 6, dd = n & 63;
#pragma unroll
      for (int mi = 0; mi < 4; ++mi) {
        const int mb = m0 + wr*64 + mi*16 + quad*4;
        const int b = mb >> 11, s = mb & 2047;
        floatx4 d = acc[mi][nj];
        u16* dst = (u16*)outv + (((size_t)b*NHEAD + h)*DK + dd)*SEQ + s;
        *(uint2*)dst = make_uint2(pkh(d[0]+bvv, d[1]+bvv), pkh(d[2]+bvv, d[3]+bvv));
      }
    }
  }
}

// ---------------------------------------------------------------------------
// MFMA flash attention. Grid (64 bh, 16 pid), 256 thr = 4 waves, 16 q/wave.
// XCD locality: flat = bh + 64*pid -> XCD = bh%8; each bh's 16 blocks
// colocate, K/V (512 KB/bh) stay L2-resident.  [r8-measured: 118 us,
// FETCH 37 MB, Occupancy 40%, MfmaUtil 18 — do not touch]
// Balanced pairing: block pid handles query-blocks {31-pid, pid} -> every
// block runs exactly 33 K-tile iterations (uniform makespan).
//  phase 1: S^T = K·Q^T (16x16x32 f16); C: col=query=lane&15, row=key.
//  softmax: per-query stats; l kept per-lane-partial, reduced in epilogue.
//  phase 2: O^T = V^T·P^T (16x16x16 f16); P^T B-frag == S^T C-layout.
// Wave-uniform ktmax skips fully-masked 16-key subtiles on the diagonal.
// ---------------------------------------------------------------------------
__global__ __launch_bounds__(256, 6)
void attn_fwd(const _Float16* __restrict__ Q, const _Float16* __restrict__ K,
              const _Float16* __restrict__ Vt, u16* __restrict__ O)
{
  __shared__ __align__(16) _Float16 Ks[64][72];
  __shared__ __align__(16) _Float16 Vs[64][72];

  const int bh   = blockIdx.x;              // 0..63  (bh%8 = home XCD)
  const int pid  = blockIdx.y;              // 0..15
  const int t    = threadIdx.x;
  const int w    = t >> 6, lane = t & 63;
  const int quad = lane >> 4, l15 = lane & 15;
  const int sr = t >> 3, sc8 = (t & 7) * 8;
  const _Float16* Kb = K  + (size_t)bh * SEQ * DK;
  const _Float16* Vb = Vt + (size_t)bh * DK * SEQ;

#pragma unroll 1
  for (int item = 0; item < 2; ++item) {
    const int rblk = item ? pid : (SEQ/64 - 1 - pid);   // heavy half first
    const int r0   = rblk * 64;
    const int qb   = r0 + w * 16;
    const int query = qb + l15;

    half8_t qf[2];
    {
      const _Float16* Qp = Q + ((size_t)bh * SEQ + query) * DK + quad * 8;
      qf[0] = *(const half8_t*)(Qp);
      qf[1] = *(const half8_t*)(Qp + 32);
    }

    float mrow = -1e30f, lpart = 0.f;
    floatx4 o[4] = {};

    const int jend = r0 + 64;
    for (int j0 = 0; j0 < jend; j0 += 64) {
      __syncthreads();
      *(uint4*)&Ks[sr     ][sc8] = *(const uint4*)(Kb + (size_t)(j0 + sr     )*DK + sc8);
      *(uint4*)&Ks[sr + 32][sc8] = *(const uint4*)(Kb + (size_t)(j0 + sr + 32)*DK + sc8);
      *(uint4*)&Vs[sr     ][sc8] = *(const uint4*)(Vb + (size_t)(sr     )*SEQ + j0 + sc8);
      *(uint4*)&Vs[sr + 32][sc8] = *(const uint4*)(Vb + (size_t)(sr + 32)*SEQ + j0 + sc8);
      __syncthreads();
      if (j0 > qb + 15) continue;                      // fully masked for wave
      const int ktmax = ((qb + 15 - j0) >> 4) + 1;     // 1..4, wave-uniform

      // ---- phase 1
      floatx4 st[4];
#pragma unroll
      for (int kt = 0; kt < 4; ++kt) {
        if (kt < ktmax) {
          half8_t a0 = *(const half8_t*)&Ks[kt*16 + l15][quad*8];
          half8_t a1 = *(const half8_t*)&Ks[kt*16 + l15][32 + quad*8];
          floatx4 s = {};
          s = __builtin_amdgcn_mfma_f32_16x16x32_f16(a0, qf[0], s, 0, 0, 0);
          s = __builtin_amdgcn_mfma_f32_16x16x32_f16(a1, qf[1], s, 0, 0, 0);
          st[kt] = s;
        }
      }
      // ---- causal mask (only subtiles straddling the diagonal)
#pragma unroll
      for (int kt = 0; kt < 4; ++kt) {
        if (kt < ktmax && j0 + kt*16 + 15 > qb) {
#pragma unroll
          for (int r = 0; r < 4; ++r)
            if (j0 + kt*16 + quad*4 + r > query) st[kt][r] = -1e30f;
        }
      }
      // ---- online softmax (log2 domain; Q pre-scaled by 0.125*log2e)
      float m0 = -1e30f;
#pragma unroll
      for (int kt = 0; kt < 4; ++kt)
        if (kt < ktmax)
          m0 = fmaxf(m0, fmaxf(fmaxf(st[kt][0], st[kt][1]), fmaxf(st[kt][2], st[kt][3])));
      m0 = fmaxf(m0, __shfl_xor(m0, 16));
      m0 = fmaxf(m0, __shfl_xor(m0, 32));
      const float mn    = fmaxf(mrow, m0);
      const float alpha = exp2f(mrow - mn);            // 0 on first live tile
      mrow = mn;
      lpart *= alpha;
      half4_t pf[4];
#pragma unroll
      for (int kt = 0; kt < 4; ++kt) {
        if (kt < ktmax) {
          const float p0 = exp2f(st[kt][0] - mn), p1 = exp2f(st[kt][1] - mn);
          const float p2 = exp2f(st[kt][2] - mn), p3 = exp2f(st[kt][3] - mn);
          lpart += (p0 + p1) + (p2 + p3);
          union { half4_t h; uint2 u; } pc;
          pc.u = make_uint2(pkh(p0, p1), pkh(p2, p3));
          pf[kt] = pc.h;
        }
      }
#pragma unroll
      for (int dt = 0; dt < 4; ++dt) {
        o[dt][0] *= alpha; o[dt][1] *= alpha; o[dt][2] *= alpha; o[dt][3] *= alpha;
      }
      // ---- phase 2
#pragma unroll
      for (int dt = 0; dt < 4; ++dt)
#pragma unroll
        for (int kt = 0; kt < 4; ++kt) {
          if (kt < ktmax) {
            half4_t vf = *(const half4_t*)&Vs[dt*16 + l15][kt*16 + quad*4];
            o[dt] = __builtin_amdgcn_mfma_f32_16x16x16f16(vf, pf[kt], o[dt], 0, 0, 0);
          }
        }
    }

    // ---- epilogue: deferred l reduction, O bf16 [B,S,D]
    float l = lpart;
    l += __shfl_xor(l, 16);
    l += __shfl_xor(l, 32);
    const float inv = 1.0f / l;
    const int b = bh >> 4, h = bh & 15;
    u16* Op = O + ((size_t)(b * SEQ + query)) * D_MODEL + h * DK + quad * 4;
#pragma unroll
    for (int dt = 0; dt < 4; ++dt) {
      u32 lo = ((u32)f2bf(o[dt][1] * inv) << 16) | f2bf(o[dt][0] * inv);
      u32 hi = ((u32)f2bf(o[dt][3] * inv) << 16) | f2bf(o[dt][2] * inv);
      *(uint2*)(Op + dt * 16) = make_uint2(lo, hi);
    }
  }
}

// ---------------------------------------------------------------------------
extern "C" void kernel_launch(void* const* d_in, const int* in_sizes, int n_in,
                              void* d_out, int out_size, void* d_ws, size_t ws_size,
                              hipStream_t stream)
{
  const float* x  = (const float*)d_in[0];
  const float* Wq = (const float*)d_in[1];
  const float* bq = (const float*)d_in[2];
  const float* Wk = (const float*)d_in[3];
  const float* bk = (const float*)d_in[4];
  const float* Wv = (const float*)d_in[5];
  const float* bv = (const float*)d_in[6];
  const float* Wo = (const float*)d_in[7];
  const float* bo = (const float*)d_in[8];

  const size_t tsz = (size_t)MTOT * D_MODEL;
  u16* Qw  = (u16*)d_ws;
  u16* Kw  = Qw + tsz;
  u16* Vtw = Kw + tsz;
  u16* S3  = Vtw + tsz;      // shared slot: xb (pre-attn) then O (post-attn)

  // x -> bf16 (trunc, same rounding as the in-GEMM pk8 path)
  to_bf16<<<(MTOT*D_MODEL)/(256*8), 256, 0, stream>>>(x, S3);

  dim3 gg(MTOT/128, D_MODEL/128);              // (64 m-tiles, 8 n-tiles)
  // Q scale = 1/sqrt(dk) * log2(e): softmax runs in log2 domain
  gemm_bt<1><<<gg, 256, 0, stream>>>(S3, Wq, bq, Qw,  0.18033688f);
  gemm_bt<1><<<gg, 256, 0, stream>>>(S3, Wk, bk, Kw,  1.0f);
  gemm_bt<2><<<gg, 256, 0, stream>>>(S3, Wv, bv, Vtw, 1.0f);

  attn_fwd<<<dim3(BATCH*NHEAD, SEQ/128), 256, 0, stream>>>(
      (const _Float16*)Qw, (const _Float16*)Kw, (const _Float16*)Vtw, S3);

  gemm_bt<0><<<gg, 256, 0, stream>>>(S3, Wo, bo, d_out, 1.0f);
}

// Round 12
// 356.554 us; speedup vs baseline: 1.0255x; 1.0255x over previous
//
#include <hip/hip_runtime.h>
#include <stdint.h>

// CausalMultiHeadAttention — round 10.
// r9/r11 post-mortem: gload16 A-staging = NULL (GEMMs 62->59.5, eaten by
// to_bf16's 9 us). Revised GEMM theory: barrier-drain-bound at exactly
// 2 blocks/CU (grid 512; Occupancy pinned 25-29%, MfmaUtil=VALUBusy=9%).
// m97's 874 TF ran this structure at 4 blocks/CU (m114 implicit overlap).
// This round, ONE lever: BM=128 x BN=64 tiles, 128-thread blocks (2 waves),
// grid (64,16) = 1024 blocks = 4 blocks/CU = 4 independent barrier domains.
// Wave-level fragment/MFMA/epilogue code identical (each wave owns 64x64).
// flat%8 = m%8 keeps A-tile XCD colocation; 16 co-XCD n-blocks/m-row keep
// W L2-resident. attn byte-identical (r8-measured 118 us).
// ws: Q | K | Vt (fp16) | {xb then O} (bf16) = 67.1 MB (proven size).

#define D_MODEL 1024
#define NHEAD   16
#define DK      64
#define BATCH   4
#define SEQ     2048
#define MTOT    (BATCH*SEQ)   // 8192

typedef unsigned short u16;
typedef unsigned int   u32;
typedef __bf16    bf16x8  __attribute__((ext_vector_type(8)));
typedef float     floatx4 __attribute__((ext_vector_type(4)));
typedef __fp16    fp16x2  __attribute__((ext_vector_type(2)));
typedef _Float16  half4_t __attribute__((ext_vector_type(4)));
typedef _Float16  half8_t __attribute__((ext_vector_type(8)));

// round-to-nearest-even f32 -> bf16 (epilogue only)
__device__ __forceinline__ u16 f2bf(float f){
  union { float f; u32 u; } c; c.f = f;
  u32 x = c.u;
  x += 0x7fffu + ((x >> 16) & 1u);
  return (u16)(x >> 16);
}
// f32 pair -> packed fp16 bits (RTZ, hardware packed cvt)
__device__ __forceinline__ u32 pkh(float a, float b){
  union { fp16x2 h; u32 u; } c; c.h = __builtin_amdgcn_cvt_pkrtz(a, b); return c.u;
}
// 8 fp32 -> 8 bf16 by truncation: one v_perm per pair (staging fast path)
__device__ __forceinline__ uint4 pk8(const float* __restrict__ p){
  uint4 a = *(const uint4*)p;
  uint4 b = *(const uint4*)(p + 4);
  uint4 r;
  r.x = __builtin_amdgcn_perm(a.y, a.x, 0x07060302);
  r.y = __builtin_amdgcn_perm(a.w, a.z, 0x07060302);
  r.z = __builtin_amdgcn_perm(b.y, b.x, 0x07060302);
  r.w = __builtin_amdgcn_perm(b.w, b.z, 0x07060302);
  return r;
}
// async global->LDS, 16B per lane. LDS dest must be linear in lane order.
__device__ __forceinline__ void gload16(const void* g, void* l){
  __builtin_amdgcn_global_load_lds(
      (const __attribute__((address_space(1))) u32*)g,
      (__attribute__((address_space(3))) u32*)l, 16, 0, 0);
}

// ---------------------------------------------------------------------------
// fp32 -> bf16 trunc convert (memory-bound pre-pass for x). Exact-size grid.
// ---------------------------------------------------------------------------
__global__ __launch_bounds__(256)
void to_bf16(const float* __restrict__ s, u16* __restrict__ d)
{
  const size_t i = ((size_t)blockIdx.x * 256 + threadIdx.x) * 8;
  *(uint4*)(d + i) = pk8(s + i);
}

// ---------------------------------------------------------------------------
// GEMM: C[m,n] = (sum_k A[m,k]*W[n,k] + bias[n]) * scale.  A: MxK row-major
// bf16 (pre-converted), staged via global_load_lds.  W: NxK fp32, pk8.
// 128x64 tile, BK=32, 128 thr = 2 waves stacked in m; each wave owns a
// 64x64 output tile = 4x4 16x16x32 MFMA (code identical to the proven r5
// wave-level path; wc eliminated since the block has one n-column of waves).
// Grid (64 m-tiles, 16 n-tiles) = 1024 blocks = 4 blocks/CU.
//   MODE 0 (fp32 [m][N], d_out) / MODE 1 (fp16 [bh][s][dk]): mfma(W,A) ->
//     lane=m, regs=n-consecutive -> float4 / uint2 stores.
//   MODE 2 (fp16 [bh][dk][s], V^T): mfma(A,W) -> lane=n(dd), regs=m(s)
//     -> uint2 stores contiguous in s.
// ---------------------------------------------------------------------------
template<int MODE>
__global__ __launch_bounds__(128, 2)
void gemm_bt(const u16* __restrict__ A, const float* __restrict__ W,
             const float* __restrict__ bias, void* __restrict__ outv,
             float scale)
{
  __shared__ __align__(16) u16 As[128*32];   // 8 KB
  __shared__ __align__(16) u16 Bs[64*32];    // 4 KB

  const int t    = threadIdx.x;              // 0..127
  const int m0   = blockIdx.x * 128;
  const int n0   = blockIdx.y * 64;
  const int wid  = t >> 6, lane = t & 63;
  const int wr   = wid;                      // wave row 0..1, wc == 0
  const int quad = lane >> 4, l15 = lane & 15;

  // staging: chunk c -> row = c>>2, koff = (c&3)*8 ; LDS [row][32 u16].
  // A: c = t + 128j (j=0..3) at byte c*16 -> wave-uniform base + lane*16.
  // B: c = t + 128j (j=0..1), pk8 (fp32 -> bf16).
  const int rS = t >> 2;                     // 0..31
  const int kS = (t & 3) * 8;

  floatx4 acc[4][4] = {};

  for (int k0 = 0; k0 < D_MODEL; k0 += 32) {
    __syncthreads();
    gload16(A + (size_t)(m0 + rS      )*D_MODEL + k0 + kS, (char*)As + t*16);
    gload16(A + (size_t)(m0 + rS + 32 )*D_MODEL + k0 + kS, (char*)As + 2048 + t*16);
    gload16(A + (size_t)(m0 + rS + 64 )*D_MODEL + k0 + kS, (char*)As + 4096 + t*16);
    gload16(A + (size_t)(m0 + rS + 96 )*D_MODEL + k0 + kS, (char*)As + 6144 + t*16);
    *(uint4*)&Bs[t*8]        = pk8(W + (size_t)(n0 + rS     )*D_MODEL + k0 + kS);
    *(uint4*)&Bs[t*8 + 1024] = pk8(W + (size_t)(n0 + rS + 32)*D_MODEL + k0 + kS);
    __syncthreads();   // compiler emits vmcnt(0)+lgkmcnt(0) drain here

    bf16x8 af[4], bf[4];
#pragma unroll
    for (int i = 0; i < 4; ++i) {
      af[i] = *(const bf16x8*)&As[(wr*64 + i*16 + l15)*32 + quad*8];
      bf[i] = *(const bf16x8*)&Bs[(i*16 + l15)*32 + quad*8];
    }
#pragma unroll
    for (int mi = 0; mi < 4; ++mi)
#pragma unroll
      for (int nj = 0; nj < 4; ++nj) {
        if (MODE == 2)
          acc[mi][nj] = __builtin_amdgcn_mfma_f32_16x16x32_bf16(af[mi], bf[nj], acc[mi][nj], 0, 0, 0);
        else
          acc[mi][nj] = __builtin_amdgcn_mfma_f32_16x16x32_bf16(bf[nj], af[mi], acc[mi][nj], 0, 0, 0);
      }
  }

  if (MODE != 2) {
    // lane = m, regs = n-consecutive
#pragma unroll
    for (int nj = 0; nj < 4; ++nj) {
      const int nb = n0 + nj*16 + quad*4;
      const float4 b4 = *(const float4*)(bias + nb);
#pragma unroll
      for (int mi = 0; mi < 4; ++mi) {
        const int m = m0 + wr*64 + mi*16 + l15;
        floatx4 d = acc[mi][nj];
        const float v0 = (d[0]+b4.x)*scale, v1 = (d[1]+b4.y)*scale;
        const float v2 = (d[2]+b4.z)*scale, v3 = (d[3]+b4.w)*scale;
        if (MODE == 0) {
          float4 s4 = make_float4(v0, v1, v2, v3);
          *(float4*)((float*)outv + (size_t)m*D_MODEL + nb) = s4;
        } else {
          const int b = m >> 11, s = m & 2047, h = nb >> 6, dd = nb & 63;
          u16* dst = (u16*)outv + ((((size_t)b*NHEAD + h)*SEQ + s) << 6) + dd;
          *(uint2*)dst = make_uint2(pkh(v0, v1), pkh(v2, v3));
        }
      }
    }
  } else {
    // lane = n (dd), regs = m (s)-consecutive
#pragma unroll
    for (int nj = 0; nj < 4; ++nj) {
      const int n  = n0 + nj*16 + l15;
      const float bvv = bias[n];
      const int h = n >> 6, dd = n & 63;
#pragma unroll
      for (int mi = 0; mi < 4; ++mi) {
        const int mb = m0 + wr*64 + mi*16 + quad*4;
        const int b = mb >> 11, s = mb & 2047;
        floatx4 d = acc[mi][nj];
        u16* dst = (u16*)outv + (((size_t)b*NHEAD + h)*DK + dd)*SEQ + s;
        *(uint2*)dst = make_uint2(pkh(d[0]+bvv, d[1]+bvv), pkh(d[2]+bvv, d[3]+bvv));
      }
    }
  }
}

// ---------------------------------------------------------------------------
// MFMA flash attention. Grid (64 bh, 16 pid), 256 thr = 4 waves, 16 q/wave.
// XCD locality: flat = bh + 64*pid -> XCD = bh%8; each bh's 16 blocks
// colocate, K/V (512 KB/bh) stay L2-resident.  [r8-measured: 118 us,
// FETCH 37 MB, Occupancy 40%, MfmaUtil 18 — do not touch]
// Balanced pairing: block pid handles query-blocks {31-pid, pid} -> every
// block runs exactly 33 K-tile iterations (uniform makespan).
//  phase 1: S^T = K·Q^T (16x16x32 f16); C: col=query=lane&15, row=key.
//  softmax: per-query stats; l kept per-lane-partial, reduced in epilogue.
//  phase 2: O^T = V^T·P^T (16x16x16 f16); P^T B-frag == S^T C-layout.
// Wave-uniform ktmax skips fully-masked 16-key subtiles on the diagonal.
// ---------------------------------------------------------------------------
__global__ __launch_bounds__(256, 6)
void attn_fwd(const _Float16* __restrict__ Q, const _Float16* __restrict__ K,
              const _Float16* __restrict__ Vt, u16* __restrict__ O)
{
  __shared__ __align__(16) _Float16 Ks[64][72];
  __shared__ __align__(16) _Float16 Vs[64][72];

  const int bh   = blockIdx.x;              // 0..63  (bh%8 = home XCD)
  const int pid  = blockIdx.y;              // 0..15
  const int t    = threadIdx.x;
  const int w    = t >> 6, lane = t & 63;
  const int quad = lane >> 4, l15 = lane & 15;
  const int sr = t >> 3, sc8 = (t & 7) * 8;
  const _Float16* Kb = K  + (size_t)bh * SEQ * DK;
  const _Float16* Vb = Vt + (size_t)bh * DK * SEQ;

#pragma unroll 1
  for (int item = 0; item < 2; ++item) {
    const int rblk = item ? pid : (SEQ/64 - 1 - pid);   // heavy half first
    const int r0   = rblk * 64;
    const int qb   = r0 + w * 16;
    const int query = qb + l15;

    half8_t qf[2];
    {
      const _Float16* Qp = Q + ((size_t)bh * SEQ + query) * DK + quad * 8;
      qf[0] = *(const half8_t*)(Qp);
      qf[1] = *(const half8_t*)(Qp + 32);
    }

    float mrow = -1e30f, lpart = 0.f;
    floatx4 o[4] = {};

    const int jend = r0 + 64;
    for (int j0 = 0; j0 < jend; j0 += 64) {
      __syncthreads();
      *(uint4*)&Ks[sr     ][sc8] = *(const uint4*)(Kb + (size_t)(j0 + sr     )*DK + sc8);
      *(uint4*)&Ks[sr + 32][sc8] = *(const uint4*)(Kb + (size_t)(j0 + sr + 32)*DK + sc8);
      *(uint4*)&Vs[sr     ][sc8] = *(const uint4*)(Vb + (size_t)(sr     )*SEQ + j0 + sc8);
      *(uint4*)&Vs[sr + 32][sc8] = *(const uint4*)(Vb + (size_t)(sr + 32)*SEQ + j0 + sc8);
      __syncthreads();
      if (j0 > qb + 15) continue;                      // fully masked for wave
      const int ktmax = ((qb + 15 - j0) >> 4) + 1;     // 1..4, wave-uniform

      // ---- phase 1
      floatx4 st[4];
#pragma unroll
      for (int kt = 0; kt < 4; ++kt) {
        if (kt < ktmax) {
          half8_t a0 = *(const half8_t*)&Ks[kt*16 + l15][quad*8];
          half8_t a1 = *(const half8_t*)&Ks[kt*16 + l15][32 + quad*8];
          floatx4 s = {};
          s = __builtin_amdgcn_mfma_f32_16x16x32_f16(a0, qf[0], s, 0, 0, 0);
          s = __builtin_amdgcn_mfma_f32_16x16x32_f16(a1, qf[1], s, 0, 0, 0);
          st[kt] = s;
        }
      }
      // ---- causal mask (only subtiles straddling the diagonal)
#pragma unroll
      for (int kt = 0; kt < 4; ++kt) {
        if (kt < ktmax && j0 + kt*16 + 15 > qb) {
#pragma unroll
          for (int r = 0; r < 4; ++r)
            if (j0 + kt*16 + quad*4 + r > query) st[kt][r] = -1e30f;
        }
      }
      // ---- online softmax (log2 domain; Q pre-scaled by 0.125*log2e)
      float m0 = -1e30f;
#pragma unroll
      for (int kt = 0; kt < 4; ++kt)
        if (kt < ktmax)
          m0 = fmaxf(m0, fmaxf(fmaxf(st[kt][0], st[kt][1]), fmaxf(st[kt][2], st[kt][3])));
      m0 = fmaxf(m0, __shfl_xor(m0, 16));
      m0 = fmaxf(m0, __shfl_xor(m0, 32));
      const float mn    = fmaxf(mrow, m0);
      const float alpha = exp2f(mrow - mn);            // 0 on first live tile
      mrow = mn;
      lpart *= alpha;
      half4_t pf[4];
#pragma unroll
      for (int kt = 0; kt < 4; ++kt) {
        if (kt < ktmax) {
          const float p0 = exp2f(st[kt][0] - mn), p1 = exp2f(st[kt][1] - mn);
          const float p2 = exp2f(st[kt][2] - mn), p3 = exp2f(st[kt][3] - mn);
          lpart += (p0 + p1) + (p2 + p3);
          union { half4_t h; uint2 u; } pc;
          pc.u = make_uint2(pkh(p0, p1), pkh(p2, p3));
          pf[kt] = pc.h;
        }
      }
#pragma unroll
      for (int dt = 0; dt < 4; ++dt) {
        o[dt][0] *= alpha; o[dt][1] *= alpha; o[dt][2] *= alpha; o[dt][3] *= alpha;
      }
      // ---- phase 2
#pragma unroll
      for (int dt = 0; dt < 4; ++dt)
#pragma unroll
        for (int kt = 0; kt < 4; ++kt) {
          if (kt < ktmax) {
            half4_t vf = *(const half4_t*)&Vs[dt*16 + l15][kt*16 + quad*4];
            o[dt] = __builtin_amdgcn_mfma_f32_16x16x16f16(vf, pf[kt], o[dt], 0, 0, 0);
          }
        }
    }

    // ---- epilogue: deferred l reduction, O bf16 [B,S,D]
    float l = lpart;
    l += __shfl_xor(l, 16);
    l += __shfl_xor(l, 32);
    const float inv = 1.0f / l;
    const int b = bh >> 4, h = bh & 15;
    u16* Op = O + ((size_t)(b * SEQ + query)) * D_MODEL + h * DK + quad * 4;
#pragma unroll
    for (int dt = 0; dt < 4; ++dt) {
      u32 lo = ((u32)f2bf(o[dt][1] * inv) << 16) | f2bf(o[dt][0] * inv);
      u32 hi = ((u32)f2bf(o[dt][3] * inv) << 16) | f2bf(o[dt][2] * inv);
      *(uint2*)(Op + dt * 16) = make_uint2(lo, hi);
    }
  }
}

// ---------------------------------------------------------------------------
extern "C" void kernel_launch(void* const* d_in, const int* in_sizes, int n_in,
                              void* d_out, int out_size, void* d_ws, size_t ws_size,
                              hipStream_t stream)
{
  const float* x  = (const float*)d_in[0];
  const float* Wq = (const float*)d_in[1];
  const float* bq = (const float*)d_in[2];
  const float* Wk = (const float*)d_in[3];
  const float* bk = (const float*)d_in[4];
  const float* Wv = (const float*)d_in[5];
  const float* bv = (const float*)d_in[6];
  const float* Wo = (const float*)d_in[7];
  const float* bo = (const float*)d_in[8];

  const size_t tsz = (size_t)MTOT * D_MODEL;
  u16* Qw  = (u16*)d_ws;
  u16* Kw  = Qw + tsz;
  u16* Vtw = Kw + tsz;
  u16* S3  = Vtw + tsz;      // shared slot: xb (pre-attn) then O (post-attn)

  // x -> bf16 (trunc, same rounding as the in-GEMM pk8 path)
  to_bf16<<<(MTOT*D_MODEL)/(256*8), 256, 0, stream>>>(x, S3);

  dim3 gg(MTOT/128, D_MODEL/64);               // (64 m-tiles, 16 n-tiles)
  // Q scale = 1/sqrt(dk) * log2(e): softmax runs in log2 domain
  gemm_bt<1><<<gg, 128, 0, stream>>>(S3, Wq, bq, Qw,  0.18033688f);
  gemm_bt<1><<<gg, 128, 0, stream>>>(S3, Wk, bk, Kw,  1.0f);
  gemm_bt<2><<<gg, 128, 0, stream>>>(S3, Wv, bv, Vtw, 1.0f);

  attn_fwd<<<dim3(BATCH*NHEAD, SEQ/128), 256, 0, stream>>>(
      (const _Float16*)Qw, (const _Float16*)Kw, (const _Float16*)Vtw, S3);

  gemm_bt<0><<<gg, 128, 0, stream>>>(S3, Wo, bo, d_out, 1.0f);
}